// Round 18
// baseline (612.461 us; speedup 1.0000x reference)
//
#include <hip/hip_runtime.h>
#include <stdint.h>

#define N_NODES 100000
#define N_EDGES 1000000
#define NBLK 391   // ceil(N_NODES/256)

typedef unsigned short u16;
typedef unsigned int u32;
typedef __attribute__((ext_vector_type(8))) short bshort8;
typedef __attribute__((ext_vector_type(4))) float f32x4;

__device__ __forceinline__ float bf2f(u16 u){ union{float f; u32 i;} x; x.i=((u32)u)<<16; return x.f; }
__device__ __forceinline__ u16 f2bf(float f){ union{float f; u32 i;} x; x.f=f; u32 r = x.i + 0x7FFFu + ((x.i>>16)&1u); return (u16)(r>>16); }

__device__ __forceinline__ float fexp2(float x){
#if __has_builtin(__builtin_amdgcn_exp2f)
    return __builtin_amdgcn_exp2f(x);
#else
    return exp2f(x);
#endif
}
__device__ __forceinline__ float frcp(float x){
#if __has_builtin(__builtin_amdgcn_rcpf)
    return __builtin_amdgcn_rcpf(x);
#else
    return 1.0f/x;
#endif
}
#define LOG2E 1.442695041f

// ---------------- dtype detector (f32 vs bf16 device buffers) ----------------
__global__ void k_detect(const u16* __restrict__ x, int* flagp){
    __shared__ int cnt;
    if(threadIdx.x == 0) cnt = 0;
    __syncthreads();
    int c = 0;
    for(int i = threadIdx.x; i < 2048; i += 256){
        int e = (x[i] >> 7) & 0xFF;
        if(e >= 0x90) c++;
    }
    atomicAdd(&cnt, c);
    __syncthreads();
    if(threadIdx.x == 0) flagp[0] = (cnt > 64) ? 1 : 0;   // 1 = f32, 0 = bf16
}

// canonical f32 table offsets
#define CX    0
#define CW1   800000
#define CB1   800512
#define CW2   800576
#define CB2   804672
#define CEMB  804736
#define CWIH  808832
#define CWHH  821120
#define CBIH  833408
#define CBHH  833600
#define CL1W  833792
#define CL1B  841984
#define CLTW  842048
#define CLTB  850240
#define CLFW  850304
#define CLFB  850560
#define CTOT  850562

__device__ __forceinline__ float ldany(const void* p, int i, int fl){
    return fl ? ((const float*)p)[i] : bf2f(((const u16*)p)[i]);
}

// ---------------- merged tables kernel: convert + 6x packb + gitab + hist ----------------
#define NCONV 3323                  // ceil(CTOT/256)
#define B_W2  (NCONV)               // 16 blocks  (64x64)
#define B_WHH (B_W2 + 16)           // 48 blocks  (64x192)
#define B_L1A (B_WHH + 48)          // 16
#define B_L1B (B_L1A + 16)          // 16
#define B_LTA (B_L1B + 16)          // 16
#define B_LTB (B_LTA + 16)          // 16
#define B_GIT (B_LTB + 16)          // 48 blocks  (64x192)
#define B_HIST (B_GIT + 48)         // 3907 blocks (1M edges)
#define B_TOT (B_HIST + 3907)

__device__ __forceinline__ void packb_dev(const void* src, u16* dst,
                                          int K, int N, int ldk, int ldn,
                                          int fl, int i){
    if(i >= K*N) return;
    int k = i / N, n = i % N;
    int kt = k >> 5, kk = k & 31, q = kk >> 3, j = kk & 7;
    int nt = n >> 4, nn = n & 15;
    int KT = K >> 5;
    dst[(((nt*KT + kt)*64) + (q*16 + nn))*8 + j] = f2bf(ldany(src, k*ldk + n*ldn, fl));
}

__global__ void k_tables(const int* __restrict__ flagp,
                         const void* x, const void* w1, const void* b1, const void* w2,
                         const void* b2, const void* emb, const void* wih, const void* whh,
                         const void* bih, const void* bhh, const void* l1w, const void* l1b,
                         const void* ltw, const void* ltb, const void* lfw, const void* lfb,
                         const int* __restrict__ ei, int* __restrict__ deg,
                         float* __restrict__ canon,
                         u16* __restrict__ w2p, u16* __restrict__ whhp,
                         u16* __restrict__ l1pa, u16* __restrict__ l1pb,
                         u16* __restrict__ ltpa, u16* __restrict__ ltpb,
                         float* __restrict__ giT){
    int b = blockIdx.x, tid = threadIdx.x;
    int fl = *flagp;
    if(b < NCONV){
        int i = b*256 + tid;
        if(i >= CTOT) return;
        const void* p; int off;
        if     (i < CW1 ){ p = x;   off = i;        }
        else if(i < CB1 ){ p = w1;  off = i - CW1;  }
        else if(i < CW2 ){ p = b1;  off = i - CB1;  }
        else if(i < CB2 ){ p = w2;  off = i - CW2;  }
        else if(i < CEMB){ p = b2;  off = i - CB2;  }
        else if(i < CWIH){ p = emb; off = i - CEMB; }
        else if(i < CWHH){ p = wih; off = i - CWIH; }
        else if(i < CBIH){ p = whh; off = i - CWHH; }
        else if(i < CBHH){ p = bih; off = i - CBIH; }
        else if(i < CL1W){ p = bhh; off = i - CBHH; }
        else if(i < CL1B){ p = l1w; off = i - CL1W; }
        else if(i < CLTW){ p = l1b; off = i - CL1B; }
        else if(i < CLTB){ p = ltw; off = i - CLTW; }
        else if(i < CLFW){ p = ltb; off = i - CLTB; }
        else if(i < CLFB){ p = lfw; off = i - CLFW; }
        else             { p = lfb; off = i - CLFB; }
        float v = ldany(p, off, fl);
        canon[i] = (v == v && fabsf(v) < 1e30f) ? v : 0.f;
    }else if(b < B_WHH){
        packb_dev(w2, w2p, 64, 64, 64, 1, fl, (b - B_W2)*256 + tid);
    }else if(b < B_L1A){
        packb_dev(whh, whhp, 64, 192, 1, 64, fl, (b - B_WHH)*256 + tid);
    }else if(b < B_L1B){
        packb_dev(l1w, l1pa, 64, 64, 1, 128, fl, (b - B_L1A)*256 + tid);
    }else if(b < B_LTA){
        packb_dev((const void*)((const char*)l1w + (fl ? 64*4 : 64*2)),
                  l1pb, 64, 64, 1, 128, fl, (b - B_L1B)*256 + tid);
    }else if(b < B_LTB){
        packb_dev(ltw, ltpa, 64, 64, 1, 128, fl, (b - B_LTA)*256 + tid);
    }else if(b < B_GIT){
        packb_dev((const void*)((const char*)ltw + (fl ? 64*4 : 64*2)),
                  ltpb, 64, 64, 1, 128, fl, (b - B_LTB)*256 + tid);
    }else if(b < B_HIST){
        // gi table, transposed: giT[v][g3][col][t];  b_hh folded for r,z (g3<2)
        int i = (b - B_GIT)*256 + tid;
        if(i >= 64*192) return;
        int v = i / 192, g = i % 192;
        float acc = ldany(bih, g, fl) + ((g < 128) ? ldany(bhh, g, fl) : 0.0f);
        for(int f = 0; f < 64; f++) acc += ldany(wih, g*64 + f, fl) * ldany(emb, v*64 + f, fl);
        int g3 = g >> 6, rem = g & 63, t = rem >> 4, col = rem & 15;
        giT[(((size_t)v*3 + g3)*16 + col)*4 + t] = acc;
    }else{
        // degree histogram (deg pre-zeroed by memset before this kernel)
        int e = (b - B_HIST)*256 + tid;
        if(e < N_EDGES) atomicAdd(&deg[ei[N_EDGES + e]], 1);
    }
}

// ---------------- CSR build: scan -> fill (el, dl, eid) ----------------
__global__ void k_scan1(const int* __restrict__ deg, int* __restrict__ rowptr,
                        int* __restrict__ bsum){
    __shared__ int sh[256];
    int tid = threadIdx.x;
    int i = blockIdx.x*256 + tid;
    int v = (i < N_NODES) ? deg[i] : 0;
    sh[tid] = v;
    __syncthreads();
    for(int off = 1; off < 256; off <<= 1){
        int t = (tid >= off) ? sh[tid - off] : 0;
        __syncthreads();
        sh[tid] += t;
        __syncthreads();
    }
    if(i < N_NODES) rowptr[i] = sh[tid] - v;
    if(tid == 255) bsum[blockIdx.x] = sh[255];
}
__global__ void k_scan2(int* __restrict__ bsum){
    __shared__ int sh[512];
    int tid = threadIdx.x;
    int v = (tid < NBLK) ? bsum[tid] : 0;
    sh[tid] = v;
    __syncthreads();
    for(int off = 1; off < 512; off <<= 1){
        int t = (tid >= off) ? sh[tid - off] : 0;
        __syncthreads();
        sh[tid] += t;
        __syncthreads();
    }
    if(tid < NBLK) bsum[tid] = sh[tid] - v;
}
// scan3 + xs = f32 x*dinv (8 feats/node; rank-8 trick, f32 for replay-stable numerics)
__global__ void k_scan3(const int* __restrict__ deg, const int* __restrict__ bsum,
                        int* __restrict__ rowptr, int* __restrict__ cursor,
                        float* __restrict__ dinv, const float* __restrict__ cx,
                        float* __restrict__ xs){
    int i = blockIdx.x*256 + threadIdx.x;
    if(i < N_NODES){
        int r = rowptr[i] + bsum[i >> 8];
        rowptr[i] = r;
        cursor[i] = r;
        float dv = rsqrtf((float)deg[i] + 1.0f);   // +1 self loop
        dinv[i] = dv;
        const float* xr = cx + (size_t)i*8;
        float* xo = xs + (size_t)i*8;
        #pragma unroll
        for(int k = 0; k < 8; k++) xo[k] = xr[k]*dv;
    }
    if(i == 0) rowptr[N_NODES] = N_EDGES;
}
__global__ void k_fill(const int* __restrict__ ei, int* __restrict__ cursor,
                       int* __restrict__ el, int* __restrict__ dl, int* __restrict__ eid){
    int e = blockIdx.x*256 + threadIdx.x;
    if(e < N_EDGES){
        int s = ei[e], d = ei[N_EDGES + e];
        int pos = atomicAdd(&cursor[d], 1);
        el[pos] = s;
        dl[pos] = d;
        eid[pos] = e;
    }
}

// ---------------- layer-1 gather on 8 feats (f32): agg8[n] = xs[n] + sum xs[neighbors] ----------------
__global__ __launch_bounds__(256)
void k_gather8(const int* __restrict__ rowptr, const int* __restrict__ el,
               const float* __restrict__ xs, float* __restrict__ agg8){
    int gid = blockIdx.x*256 + threadIdx.x;
    int node = gid >> 2, fp = (gid & 3)*2;
    if(node >= N_NODES) return;               // tail guard
    int beg = rowptr[node], end = rowptr[node + 1];
    float2 self = *(const float2*)(xs + (size_t)node*8 + fp);
    float a0 = self.x, a1 = self.y;
    int i = beg;
    for(; i + 4 <= end; i += 4){
        int s0 = el[i], s1 = el[i+1], s2 = el[i+2], s3 = el[i+3];
        float2 v0 = *(const float2*)(xs + (size_t)s0*8 + fp);
        float2 v1 = *(const float2*)(xs + (size_t)s1*8 + fp);
        float2 v2 = *(const float2*)(xs + (size_t)s2*8 + fp);
        float2 v3 = *(const float2*)(xs + (size_t)s3*8 + fp);
        a0 += v0.x; a1 += v0.y;
        a0 += v1.x; a1 += v1.y;
        a0 += v2.x; a1 += v2.y;
        a0 += v3.x; a1 += v3.y;
    }
    for(; i < end; i++){
        float2 v = *(const float2*)(xs + (size_t)el[i]*8 + fp);
        a0 += v.x; a1 += v.y;
    }
    float2 o; o.x = a0; o.y = a1;
    *(float2*)(agg8 + (size_t)node*8 + fp) = o;
}

// ---------------- conv1 epilogue: h1 = bf16(relu(dinv*(agg8 @ W1) + b1)) ----------------
__global__ void k_conv1(const float* __restrict__ agg8, const float* __restrict__ cw1,
                        const float* __restrict__ dinv, const float* __restrict__ b1,
                        u16* __restrict__ h1){
    __shared__ float w[512];
    int t = threadIdx.x;
    w[t]       = cw1[t];
    w[t + 256] = cw1[t + 256];
    __syncthreads();
    int i = blockIdx.x*256 + t;      // grid exactly N*64/256
    int n = i >> 6, f = i & 63;
    const float* ar = agg8 + (size_t)n*8;
    float acc = 0.f;
    #pragma unroll
    for(int k = 0; k < 8; k++) acc += ar[k] * w[k*64 + f];
    h1[(size_t)n*64 + f] = f2bf(fmaxf(dinv[n]*acc + b1[f], 0.f));
}

// ---------------- layer-2 fused gather + epilogue: u32 loads, 2 feats/thread ----------------
__global__ __launch_bounds__(256)
void k_gather_ep(const int* __restrict__ rowptr, const int* __restrict__ el,
                 const u16* __restrict__ src, const float* __restrict__ dinv,
                 const float* __restrict__ b, u16* __restrict__ h, int ostride){
    int gid = blockIdx.x*256 + threadIdx.x;   // grid exactly N*32/256
    int node = gid >> 5, fp = (gid & 31)*2;
    int beg = rowptr[node], end = rowptr[node + 1];
    u32 self = *(const u32*)(src + (size_t)node*64 + fp);
    float acc0 = bf2f((u16)self), acc1 = bf2f((u16)(self >> 16));
    int i = beg;
    for(; i + 4 <= end; i += 4){
        int s0 = el[i], s1 = el[i+1], s2 = el[i+2], s3 = el[i+3];
        u32 a0 = *(const u32*)(src + (size_t)s0*64 + fp);
        u32 a1 = *(const u32*)(src + (size_t)s1*64 + fp);
        u32 a2 = *(const u32*)(src + (size_t)s2*64 + fp);
        u32 a3 = *(const u32*)(src + (size_t)s3*64 + fp);
        acc0 += bf2f((u16)a0); acc1 += bf2f((u16)(a0 >> 16));
        acc0 += bf2f((u16)a1); acc1 += bf2f((u16)(a1 >> 16));
        acc0 += bf2f((u16)a2); acc1 += bf2f((u16)(a2 >> 16));
        acc0 += bf2f((u16)a3); acc1 += bf2f((u16)(a3 >> 16));
    }
    for(; i < end; i++){
        u32 a = *(const u32*)(src + (size_t)el[i]*64 + fp);
        acc0 += bf2f((u16)a); acc1 += bf2f((u16)(a >> 16));
    }
    float dv = dinv[node];
    float r0 = fmaxf(dv*acc0 + b[fp],     0.f);
    float r1 = fmaxf(dv*acc1 + b[fp + 1], 0.f);
    *(u32*)(h + (size_t)node*ostride + fp) = (u32)f2bf(r0) | ((u32)f2bf(r1) << 16);
}

// ---------------- conv2 GEMM: src = bf16((h1 @ W2) * dinv) ----------------
__global__ __launch_bounds__(256, 4)
void k_conv2(const u16* __restrict__ h, const u16* __restrict__ w2p,
             const float* __restrict__ dinv, u16* __restrict__ src){
    int wv = threadIdx.x >> 6, lane = threadIdx.x & 63;
    int g = blockIdx.x*4 + wv;
    if(g >= N_NODES/16) return;
    int q = lane >> 4, m = lane & 15, col = m;
    bshort8 a0 = *(const bshort8*)(h + (g*16 + m)*64 + q*8);
    bshort8 a1 = *(const bshort8*)(h + (g*16 + m)*64 + 32 + q*8);
    f32x4 acc[4];
    #pragma unroll
    for(int nt = 0; nt < 4; nt++){
        f32x4 c = {0.f,0.f,0.f,0.f};
        c = __builtin_amdgcn_mfma_f32_16x16x32_bf16(a0, *(const bshort8*)(w2p + ((nt*2+0)*64 + lane)*8), c, 0,0,0);
        c = __builtin_amdgcn_mfma_f32_16x16x32_bf16(a1, *(const bshort8*)(w2p + ((nt*2+1)*64 + lane)*8), c, 0,0,0);
        acc[nt] = c;
    }
    #pragma unroll
    for(int nt = 0; nt < 4; nt++)
        #pragma unroll
        for(int r = 0; r < 4; r++){
            int node = g*16 + q*4 + r;
            src[node*64 + nt*16 + col] = f2bf(acc[nt][r] * dinv[node]);
        }
}

// ---------------- GRU + pair precompute, fused; 512-thread blocks share one Whh LDS copy ----
// LDS/block = 24576 (wsh) + 8*2304 (h tiles) = 43008 B -> 3 blocks/CU = 24 waves (75% cap,
// up from 4x256-thread blocks = 16 waves). R17 post-mortem: k_gru is issue-bound at the
// occupancy cap, not gi-load-latency bound.
__global__ __launch_bounds__(512, 6)
void k_gru(const int* __restrict__ xt, const u16* __restrict__ whhp,
           const float* __restrict__ giT, const float* __restrict__ bhh,
           u16* nodef, u32* __restrict__ udst,
           const u16* __restrict__ w1a, const u16* __restrict__ w1b,
           const u16* __restrict__ wta, const u16* __restrict__ wtb,
           const float* __restrict__ b1, const float* __restrict__ bt){
    __shared__ __align__(16) u16 wsh[12288];        // 24 KB Whh frags (shared by 8 waves)
    __shared__ __align__(16) u16 hsh[8][16][72];    // bf16 h tile per wave
    int tid = threadIdx.x;
    {
        const uint4* s = (const uint4*)whhp;
        uint4* d = (uint4*)wsh;
        #pragma unroll
        for(int i = 0; i < 3; i++) d[tid + 512*i] = s[tid + 512*i];
    }
    __syncthreads();

    int wv = tid >> 6, lane = tid & 63;
    int q = lane >> 4, m = lane & 15, col = m;
    int g = blockIdx.x*8 + wv;
    bool active = g < (N_NODES/16);
    int nb = active ? g*16 : 0;

    float bhhn[4];
    #pragma unroll
    for(int t = 0; t < 4; t++) bhhn[t] = bhh[128 + t*16 + col];

    const bshort8* wl = (const bshort8*)wsh;
    const u16* hp = &hsh[wv][m][0];

    float hc[4][4];
    #pragma unroll
    for(int t = 0; t < 4; t++)
        #pragma unroll
        for(int r = 0; r < 4; r++) hc[t][r] = 0.f;

    for(int s = 0; s < 10; s++){
        #pragma unroll
        for(int t = 0; t < 4; t++)
            #pragma unroll
            for(int r = 0; r < 4; r++)
                hsh[wv][q*4 + r][t*16 + col] = f2bf(hc[t][r]);

        asm volatile("" ::: "memory");
        bshort8 a0 = *(const bshort8*)(hp + q*8);
        bshort8 a1 = *(const bshort8*)(hp + 32 + q*8);

        int tok[4];
        #pragma unroll
        for(int r = 0; r < 4; r++) tok[r] = xt[(nb + q*4 + r)*10 + s] & 63;

        f32x4 acc[12];
        #pragma unroll
        for(int nt = 0; nt < 12; nt++){
            f32x4 c = {0.f,0.f,0.f,0.f};
            c = __builtin_amdgcn_mfma_f32_16x16x32_bf16(a0, wl[(nt*2+0)*64 + lane], c, 0,0,0);
            c = __builtin_amdgcn_mfma_f32_16x16x32_bf16(a1, wl[(nt*2+1)*64 + lane], c, 0,0,0);
            acc[nt] = c;
        }

        #pragma unroll
        for(int r = 0; r < 4; r++){
            const float4* gp = (const float4*)(giT + (size_t)tok[r]*192);
            float4 gr = gp[col];
            float4 gz = gp[16 + col];
            float4 gn = gp[32 + col];
            #pragma unroll
            for(int t = 0; t < 4; t++){
                float gir = ((const float*)&gr)[t];
                float giz = ((const float*)&gz)[t];
                float gin = ((const float*)&gn)[t];
                float rr = frcp(1.0f + fexp2(-LOG2E*(gir + acc[t][r])));
                float zz = frcp(1.0f + fexp2(-LOG2E*(giz + acc[4+t][r])));
                float narg = gin + rr*(acc[8+t][r] + bhhn[t]);
                float e2 = fexp2(2.0f*LOG2E*narg);
                float nn = 1.0f - 2.0f*frcp(e2 + 1.0f);
                hc[t][r] = nn + zz*(hc[t][r] - nn);
            }
        }
        asm volatile("" ::: "memory");
    }

    // ---- fused pair precompute ----
    #pragma unroll
    for(int t = 0; t < 4; t++)
        #pragma unroll
        for(int r = 0; r < 4; r++)
            hsh[wv][q*4 + r][t*16 + col] = f2bf(hc[t][r]);   // txt tile
    asm volatile("" ::: "memory");
    bshort8 at0 = *(const bshort8*)(hp + q*8);
    bshort8 at1 = *(const bshort8*)(hp + 32 + q*8);
    const u16* row = nodef + (size_t)(nb + m)*128;           // h2 rows
    bshort8 ah0 = *(const bshort8*)(row + q*8);
    bshort8 ah1 = *(const bshort8*)(row + 32 + q*8);

    u32* usrc = (u32*)nodef;
    #pragma unroll
    for(int nt = 0; nt < 4; nt++){
        f32x4 cu1 = {0.f,0.f,0.f,0.f}, cu2 = {0.f,0.f,0.f,0.f};
        f32x4 cv1 = {0.f,0.f,0.f,0.f}, cv2 = {0.f,0.f,0.f,0.f};
        cu1 = __builtin_amdgcn_mfma_f32_16x16x32_bf16(ah0, *(const bshort8*)(w1a + ((nt*2+0)*64 + lane)*8), cu1, 0,0,0);
        cu1 = __builtin_amdgcn_mfma_f32_16x16x32_bf16(ah1, *(const bshort8*)(w1a + ((nt*2+1)*64 + lane)*8), cu1, 0,0,0);
        cu2 = __builtin_amdgcn_mfma_f32_16x16x32_bf16(ah0, *(const bshort8*)(w1b + ((nt*2+0)*64 + lane)*8), cu2, 0,0,0);
        cu2 = __builtin_amdgcn_mfma_f32_16x16x32_bf16(ah1, *(const bshort8*)(w1b + ((nt*2+1)*64 + lane)*8), cu2, 0,0,0);
        cv1 = __builtin_amdgcn_mfma_f32_16x16x32_bf16(at0, *(const bshort8*)(wta + ((nt*2+0)*64 + lane)*8), cv1, 0,0,0);
        cv1 = __builtin_amdgcn_mfma_f32_16x16x32_bf16(at1, *(const bshort8*)(wta + ((nt*2+1)*64 + lane)*8), cv1, 0,0,0);
        cv2 = __builtin_amdgcn_mfma_f32_16x16x32_bf16(at0, *(const bshort8*)(wtb + ((nt*2+0)*64 + lane)*8), cv2, 0,0,0);
        cv2 = __builtin_amdgcn_mfma_f32_16x16x32_bf16(at1, *(const bshort8*)(wtb + ((nt*2+1)*64 + lane)*8), cv2, 0,0,0);
        if(active){
            int f = nt*16 + col;
            float b1f = b1[f], btf = bt[f];
            #pragma unroll
            for(int r = 0; r < 4; r++){
                int node = nb + q*4 + r;
                u32 pa = (u32)f2bf(cu1[r] + b1f) | ((u32)f2bf(cv1[r] + btf) << 16);
                u32 pb = (u32)f2bf(cu2[r]) | ((u32)f2bf(cv2[r]) << 16);
                usrc[(size_t)node*64 + f] = pa;
                udst[(size_t)node*64 + f] = pb;
            }
        }
    }
}

// ---------------- edge kernel: uint4 row loads; 4 edges/wave, 16 lanes/edge ----------------
__global__ __launch_bounds__(256, 6)
void k_edge2(const int* __restrict__ el, const int* __restrict__ dl, const int* __restrict__ eid,
             const u32* __restrict__ usrc, const u32* __restrict__ udst,
             const float* __restrict__ wfin, const float* __restrict__ bfin,
             const int* __restrict__ flagp, void* __restrict__ out){
    int tid = threadIdx.x;
    int lane = tid & 63;
    int q = lane >> 4, f0 = lane & 15;
    int wid = (blockIdx.x*256 + tid) >> 6;
    int nwv = (gridDim.x*256) >> 6;
    int fl = *flagp;

    float wp0[4], wp1[4], wt0[4], wt1[4];
    #pragma unroll
    for(int t = 0; t < 4; t++){
        int f = 4*f0 + t;
        wp0[t] = wfin[f];        wt0[t] = wfin[64 + f];
        wp1[t] = wfin[128 + f];  wt1[t] = wfin[192 + f];
    }
    float bf0 = bfin[0], bf1 = bfin[1];

    for(int grp = wid; grp < N_EDGES/4; grp += nwv){
        int e = grp*4 + q;
        int s = el[e], d = dl[e];
        uint4 us4 = *((const uint4*)(usrc + (size_t)s*64) + f0);
        uint4 ud4 = *((const uint4*)(udst + (size_t)d*64) + f0);
        u32 us[4] = {us4.x, us4.y, us4.z, us4.w};
        u32 ud[4] = {ud4.x, ud4.y, ud4.z, ud4.w};
        float s0 = 0.f, s1 = 0.f;
        #pragma unroll
        for(int t = 0; t < 4; t++){
            float u1 = __uint_as_float(us[t] << 16);
            float v1 = __uint_as_float(us[t] & 0xffff0000u);
            float u2 = __uint_as_float(ud[t] << 16);
            float v2 = __uint_as_float(ud[t] & 0xffff0000u);
            float xp = fmaxf(u1 + u2, 0.f);
            float xq = fmaxf(v1 + v2, 0.f);
            s0 += xp*wp0[t] + xq*wt0[t];
            s1 += xp*wp1[t] + xq*wt1[t];
        }
        #pragma unroll
        for(int msk = 1; msk < 16; msk <<= 1){
            s0 += __shfl_xor(s0, msk, 64);
            s1 += __shfl_xor(s1, msk, 64);
        }
        if(f0 == 0){
            float a = s0 + bf0, b = s1 + bf1;
            float mx = fmaxf(a, b);
            float lse = mx + __logf(__expf(a - mx) + __expf(b - mx));
            int oi = eid[e];
            if(fl){
                float2 v; v.x = a - lse; v.y = b - lse;
                ((float2*)out)[oi] = v;
            }else{
                u32 pack = (u32)f2bf(a - lse) | ((u32)f2bf(b - lse) << 16);
                ((u32*)out)[oi] = pack;
            }
        }
    }
}

// ---------------- workspace layout (68.3 MB) ----------------
static const size_t O_FLAG   = 0;
static const size_t O_CANON  = 4096;       // 3,402,248
static const size_t O_GIT    = 3407872;    // 49,152
static const size_t O_W2P    = 3457024;    // 8,192
static const size_t O_WHHP   = 3465216;    // 24,576
static const size_t O_L1PA   = 3489792;    // 8,192
static const size_t O_L1PB   = 3497984;    // 8,192
static const size_t O_LTPA   = 3506176;    // 8,192
static const size_t O_LTPB   = 3514368;    // 8,192
static const size_t O_DINV   = 3522560;    // 400,000
static const size_t O_DEG    = 3922560;    // 400,000
static const size_t O_ROWPTR = 4322560;    // 400,128
static const size_t O_CURSOR = 4722688;    // 400,000
static const size_t O_BSUM   = 5122688;    // 2,048
static const size_t O_EL     = 5124736;    // 4,000,000
static const size_t O_DL     = 9125888;    // 4,000,000
static const size_t O_EID    = 13125888;   // 4,000,000
static const size_t O_SRC    = 17125888;   // N*64 bf16 (written by conv2; dead after gather_ep)
static const size_t O_XS     = 17125888;   // N*8 f32 (overlays SRC; dead before conv2 writes)
static const size_t O_AGG8   = 20325888;   // N*8 f32 (overlays SRC; dead before conv2 writes)
static const size_t O_H1     = 29925888;   // N*64 bf16 (dead after conv2)
static const size_t O_UDST   = 17125888;   // N*64 u32 (overlays SRC+H1, written in fused gru)
static const size_t O_NODEF  = 42725888;   // N*128 bf16 (h2; fused gru rewrites in-place as usrc)
// end = 68,325,888

extern "C" void kernel_launch(void* const* d_in, const int* in_sizes, int n_in,
                              void* d_out, int out_size, void* d_ws, size_t ws_size,
                              hipStream_t stream){
    const void* x    = d_in[0];
    const int*  ei   = (const int*)d_in[1];
    const int*  xt   = (const int*)d_in[2];

    char* ws = (char*)d_ws;
    int*   flagp  = (int*)(ws + O_FLAG);
    float* canon  = (float*)(ws + O_CANON);
    float* giT    = (float*)(ws + O_GIT);
    u16*   w2p    = (u16*)(ws + O_W2P);
    u16*   whhp   = (u16*)(ws + O_WHHP);
    u16*   l1pa   = (u16*)(ws + O_L1PA);
    u16*   l1pb   = (u16*)(ws + O_L1PB);
    u16*   ltpa   = (u16*)(ws + O_LTPA);
    u16*   ltpb   = (u16*)(ws + O_LTPB);
    float* dinv   = (float*)(ws + O_DINV);
    int*   deg    = (int*)(ws + O_DEG);
    int*   rowptr = (int*)(ws + O_ROWPTR);
    int*   cursor = (int*)(ws + O_CURSOR);
    int*   bsum   = (int*)(ws + O_BSUM);
    int*   el     = (int*)(ws + O_EL);
    int*   dl     = (int*)(ws + O_DL);
    int*   eid    = (int*)(ws + O_EID);
    u16*   src    = (u16*)(ws + O_SRC);
    float* xs     = (float*)(ws + O_XS);
    float* agg8   = (float*)(ws + O_AGG8);
    u16*   hbuf1  = (u16*)(ws + O_H1);
    u32*   udst   = (u32*)(ws + O_UDST);
    u16*   nodef  = (u16*)(ws + O_NODEF);

    // deg zero + dtype detect, then ALL table prep + histogram in one kernel
    hipMemsetAsync(deg, 0, (size_t)N_NODES*4, stream);
    k_detect<<<1, 256, 0, stream>>>((const u16*)x, flagp);
    k_tables<<<B_TOT, 256, 0, stream>>>(flagp,
        x, d_in[3], d_in[4], d_in[5], d_in[6], d_in[7], d_in[8], d_in[9],
        d_in[10], d_in[11], d_in[12], d_in[13], d_in[14], d_in[15], d_in[16], d_in[17],
        ei, deg,
        canon, w2p, whhp, l1pa, l1pb, ltpa, ltpb, giT);

    const float* cx   = canon + CX;
    const float* cw1  = canon + CW1;
    const float* cb1  = canon + CB1;
    const float* cb2  = canon + CB2;
    const float* cbhh = canon + CBHH;
    const float* cl1b = canon + CL1B;
    const float* cltb = canon + CLTB;
    const float* clfw = canon + CLFW;
    const float* clfb = canon + CLFB;

    // CSR build (scan3 also emits xs = x*dinv in f32)
    k_scan1<<<NBLK, 256, 0, stream>>>(deg, rowptr, bsum);
    k_scan2<<<1, 512, 0, stream>>>(bsum);
    k_scan3<<<NBLK, 256, 0, stream>>>(deg, bsum, rowptr, cursor, dinv, cx, xs);
    k_fill <<<(N_EDGES+255)/256, 256, 0, stream>>>(ei, cursor, el, dl, eid);

    // GCN layer 1 via rank-8 aggregation (f32): xs -> agg8 -> h1
    k_gather8<<<(N_NODES*4 + 255)/256, 256, 0, stream>>>(rowptr, el, xs, agg8);
    k_conv1<<<N_NODES*64/256, 256, 0, stream>>>(agg8, cw1, dinv, cb1, hbuf1);

    // GCN layer 2 (h1 -> src -> nodef[+0], stride 128)
    k_conv2<<<(N_NODES/16 + 3)/4, 256, 0, stream>>>(hbuf1, w2p, dinv, src);
    k_gather_ep<<<N_NODES*32/256, 256, 0, stream>>>(rowptr, el, src, dinv, cb2, nodef, 128);

    // GRU + pair precompute fused (512-thread blocks; nodef -> usrc in-place, udst)
    k_gru<<<(N_NODES/16 + 7)/8, 512, 0, stream>>>(xt, whhp, giT, cbhh,
                                                  nodef, udst, l1pa, l1pb, ltpa, ltpb,
                                                  cl1b, cltb);

    // edge logits + log_softmax (CSR order, scatter by eid)
    k_edge2<<<4096, 256, 0, stream>>>(el, dl, eid, (const u32*)nodef, udst,
                                      clfw, clfb, flagp, d_out);
}